// Round 10
// baseline (40.112 us; speedup 1.0000x reference)
//
#include <hip/hip_runtime.h>

#define NUM_EMBEDDINGS 50000
#define EMBEDDING_DIM  1024
#define N_CENTROIDS    256
#define N_BLOCKS       128    // EMBEDDING_DIM / 8
#define N_TOKENS       16384  // BATCH * SEQ
#define N_PARTS        8      // one per XCD
#define BLKS_PER_PART  (N_BLOCKS / N_PARTS)        // 16
#define TOKENS_PER_WG  8      // 256 threads = 8 groups of 32 lanes

typedef float f32x4 __attribute__((ext_vector_type(4)));

// R5 structure (XCD-sliced code reads + nt stores) + NON-TEMPORAL code LOADS.
//
//   part = bid & 7  -> fixed XCD; its L2 caches only blks [16p,16p+16) of
//                      assignments (3.2 MB < 4 MB), protected by nt stores.
//   nt code loads   -> the 3.2 MB/XCD code stream no longer allocates in the
//                      32 KB L1 (each line is used for 4 B exactly once), so
//                      (a) the 8 KB centroid table stays L1-resident instead
//                      of being churned out every wave, and (b) L1 MSHRs are
//                      freed for real outstanding misses.
//
// Thread (tgrp = tid>>5, lane = tid&31):
//   token = (bid>>3)*8 + tgrp
//   blk   = 16*part + (lane>>1) ; half = lane&1
//   code  = nt-load assignments[blk*NUM_EMBEDDINGS + id]   (XCD-local L2)
//   out float4 #(token*256 + part*32 + lane) = centroids float4 #(code*2+half)
__global__ __launch_bounds__(256) void pq_embed_ntld_kernel(
    const float* __restrict__ centroids,     // [256][8]
    const int*   __restrict__ assignments,   // [128][50000]
    const int*   __restrict__ input_ids,     // [16384]
    float*       __restrict__ out)           // [16384][1024]
{
    const int part  = blockIdx.x & (N_PARTS - 1);
    const int group = blockIdx.x >> 3;

    const int tid  = threadIdx.x;
    const int tgrp = tid >> 5;
    const int lane = tid & 31;

    const int token = group * TOKENS_PER_WG + tgrp;
    const int id    = input_ids[token];

    const int blk  = part * BLKS_PER_PART + (lane >> 1);
    const int half = lane & 1;

    const int code = __builtin_nontemporal_load(
        assignments + (size_t)blk * NUM_EMBEDDINGS + id);

    const f32x4 v = reinterpret_cast<const f32x4*>(centroids)[(code << 1) + half];

    f32x4* dst = reinterpret_cast<f32x4*>(out) +
                 (size_t)token * (EMBEDDING_DIM / 4) + part * 32 + lane;
    __builtin_nontemporal_store(v, dst);
}

extern "C" void kernel_launch(void* const* d_in, const int* in_sizes, int n_in,
                              void* d_out, int out_size, void* d_ws, size_t ws_size,
                              hipStream_t stream) {
    const float* centroids   = (const float*)d_in[0];
    const int*   assignments = (const int*)d_in[1];
    const int*   input_ids   = (const int*)d_in[2];
    float*       out         = (float*)d_out;

    dim3 grid((N_TOKENS / TOKENS_PER_WG) * N_PARTS);  // 16384
    dim3 block(256);
    pq_embed_ntld_kernel<<<grid, block, 0, stream>>>(centroids, assignments, input_ids, out);
}

// Round 11
// 20.128 us; speedup vs baseline: 1.9928x; 1.9928x over previous
//
#include <hip/hip_runtime.h>

#define NUM_EMBEDDINGS 50000
#define EMBEDDING_DIM  1024
#define N_CENTROIDS    256
#define N_BLOCKS       128    // EMBEDDING_DIM / 8
#define N_TOKENS       16384  // BATCH * SEQ
#define N_PARTS        8      // one per XCD
#define BLKS_PER_PART  16     // N_BLOCKS / N_PARTS
#define TOK_PER_BLOCK  64

typedef float f32x4 __attribute__((ext_vector_type(4)));

// Block-cooperative gather: decouple the id->code->centroid->store chain.
//
// Grid: 2048 blocks = 256 token-groups x 8 parts  (exactly 8 blocks/CU, all
// resident from t=0 -> zero wave churn; part = bid&7 keeps the XCD-sliced
// assignments locality: 3.2 MB slice per XCD L2, protected by nt stores).
//
// Phase A: 64 ids staged (coalesced), then 1024 scattered code loads for
//   (token, blk16) pairs issued as 4 INDEPENDENT loads per thread into LDS.
//   Latency is paid once per block in bulk (vmcnt-batched), not once per
//   store chain (R5..R8 all ran 1 dependent chain per wave -> latency-bound,
//   proven by R10's nt-load blowup).
// Phase B: pure store stream. Codes from LDS ([tok][blk16] -> 32 distinct
//   words on 32 distinct banks per wave = conflict-free, broadcast for the
//   2 half-lanes). Centroids from LDS with STRIDE-9 padding: bank =
//   (9*code+4*half+j)%32, 9 coprime 32 -> random codes spread all banks
//   (R7's null is explained: its stride-8 f32x4 layout aliased to 8 banks).
//   nt f32x4 stores (proven +6us in R3->R5).
__global__ __launch_bounds__(256) void pq_embed_coop_kernel(
    const float* __restrict__ centroids,     // [256][8]
    const int*   __restrict__ assignments,   // [128][50000]
    const int*   __restrict__ input_ids,     // [16384]
    float*       __restrict__ out)           // [16384][1024]
{
    __shared__ int   ids_lds[TOK_PER_BLOCK];
    __shared__ int   codes_lds[TOK_PER_BLOCK * BLKS_PER_PART];  // linear [tok*16+blk16]
    __shared__ float c_lds[N_CENTROIDS * 9];                    // stride-9 padded

    const int tid  = threadIdx.x;
    const int part = blockIdx.x & (N_PARTS - 1);
    const int T0   = (blockIdx.x >> 3) * TOK_PER_BLOCK;

    // --- stage centroids (coalesced float4 reads, stride-9 LDS writes) ---
    {
        const f32x4* __restrict__ cg4 = reinterpret_cast<const f32x4*>(centroids);
        #pragma unroll
        for (int k = 0; k < 2; ++k) {
            const int i = tid + 256 * k;        // float4 index 0..511
            const f32x4 v = cg4[i];
            float* dst = &c_lds[(i >> 1) * 9 + (i & 1) * 4];
            dst[0] = v.x; dst[1] = v.y; dst[2] = v.z; dst[3] = v.w;
        }
    }
    // --- stage ids (coalesced, wave 0) ---
    if (tid < TOK_PER_BLOCK)
        ids_lds[tid] = input_ids[T0 + tid];
    __syncthreads();

    // --- phase A: bulk scattered code gather, 4 independent loads/thread ---
    #pragma unroll
    for (int k = 0; k < 4; ++k) {
        const int p     = tid + 256 * k;   // pair index == linear LDS index
        const int tok   = p >> 4;
        const int blk16 = p & 15;
        const int id    = ids_lds[tok];    // LDS broadcast (16 lanes/word)
        codes_lds[p] = assignments[(size_t)(part * BLKS_PER_PART + blk16) * NUM_EMBEDDINGS + id];
    }
    __syncthreads();

    // --- phase B: stream stores ---
    const int f4    = tid & 31;   // float4 index within the token's part-slice
    const int t8    = tid >> 5;   // 0..7
    const int blk16 = f4 >> 1;
    const int half  = f4 & 1;

    f32x4* __restrict__ o4 = reinterpret_cast<f32x4*>(out);

    #pragma unroll
    for (int k = 0; k < 8; ++k) {
        const int tok  = t8 + 8 * k;
        const int code = codes_lds[tok * BLKS_PER_PART + blk16];
        const float* __restrict__ cr = &c_lds[code * 9 + half * 4];
        f32x4 v;
        v.x = cr[0]; v.y = cr[1]; v.z = cr[2]; v.w = cr[3];
        __builtin_nontemporal_store(
            v, o4 + (size_t)(T0 + tok) * (EMBEDDING_DIM / 4) + part * 32 + f4);
    }
}

extern "C" void kernel_launch(void* const* d_in, const int* in_sizes, int n_in,
                              void* d_out, int out_size, void* d_ws, size_t ws_size,
                              hipStream_t stream) {
    const float* centroids   = (const float*)d_in[0];
    const int*   assignments = (const int*)d_in[1];
    const int*   input_ids   = (const int*)d_in[2];
    float*       out         = (float*)d_out;

    dim3 grid((N_TOKENS / TOK_PER_BLOCK) * N_PARTS);  // 256 * 8 = 2048
    dim3 block(256);
    pq_embed_coop_kernel<<<grid, block, 0, stream>>>(centroids, assignments, input_ids, out);
}